// Round 2
// baseline (5077.266 us; speedup 1.0000x reference)
//
#include <hip/hip_runtime.h>
#include <hip/hip_bf16.h>
#include <math.h>

#define NROWS 8192
#define DFEAT 2048
#define KSEL  64

typedef unsigned long long u64;

__device__ __forceinline__ u64 umax64(u64 a, u64 b) { return a > b ? a : b; }

// ---------------- K1: sim panel = F[row0:row0+chunk] @ F^T  (all 8192 cols) ----------------
__global__ __launch_bounds__(256) void k_simgemm_rows(const float* __restrict__ F, float* __restrict__ C,
                                                      int row0) {
  const int bj = blockIdx.x;        // column block (0..63)
  const int bil = blockIdx.y;       // local row block within chunk
  __shared__ float As[16][136];
  __shared__ float Bs[16][136];
  const int t = threadIdx.x;
  const int tx = t & 15, ty = t >> 4;
  float acc[8][8];
#pragma unroll
  for (int i = 0; i < 8; ++i)
#pragma unroll
    for (int j = 0; j < 8; ++j) acc[i][j] = 0.f;

  const int lr = t >> 1;
  const int lc2 = (t & 1) * 2;
  const float* Abase = F + ((size_t)row0 + (size_t)bil * 128) * DFEAT;
  const float* Bbase = F + (size_t)bj * 128 * DFEAT;

  for (int k0 = 0; k0 < DFEAT; k0 += 16) {
    __syncthreads();
#pragma unroll
    for (int q = 0; q < 2; ++q) {
      const int c4 = lc2 + q;
      float4 va = *(const float4*)(Abase + (size_t)lr * DFEAT + k0 + c4 * 4);
      float4 vb = *(const float4*)(Bbase + (size_t)lr * DFEAT + k0 + c4 * 4);
      As[c4*4+0][lr] = va.x; As[c4*4+1][lr] = va.y; As[c4*4+2][lr] = va.z; As[c4*4+3][lr] = va.w;
      Bs[c4*4+0][lr] = vb.x; Bs[c4*4+1][lr] = vb.y; Bs[c4*4+2][lr] = vb.z; Bs[c4*4+3][lr] = vb.w;
    }
    __syncthreads();
#pragma unroll
    for (int k = 0; k < 16; ++k) {
      float4 a0 = *(const float4*)&As[k][ty*4];
      float4 a1 = *(const float4*)&As[k][64 + ty*4];
      float4 b0 = *(const float4*)&Bs[k][tx*4];
      float4 b1 = *(const float4*)&Bs[k][64 + tx*4];
      float ar[8] = {a0.x, a0.y, a0.z, a0.w, a1.x, a1.y, a1.z, a1.w};
      float br[8] = {b0.x, b0.y, b0.z, b0.w, b1.x, b1.y, b1.z, b1.w};
#pragma unroll
      for (int i = 0; i < 8; ++i)
#pragma unroll
        for (int j = 0; j < 8; ++j) acc[i][j] += ar[i] * br[j];
    }
  }

#pragma unroll
  for (int i = 0; i < 8; ++i) {
    const int li = bil*128 + ((i < 4) ? (ty*4 + i) : (64 + ty*4 + (i - 4)));  // local row in chunk
    float4 v0 = make_float4(acc[i][0], acc[i][1], acc[i][2], acc[i][3]);
    float4 v1 = make_float4(acc[i][4], acc[i][5], acc[i][6], acc[i][7]);
    *(float4*)(C + (size_t)li * NROWS + bj*128 + tx*4) = v0;
    *(float4*)(C + (size_t)li * NROWS + bj*128 + 64 + tx*4) = v1;
  }
}

// ---------------- K2: top-64 per row (values + indices, lower-index tie-break) + exp_sim ----------------
__global__ __launch_bounds__(256) void k_topk(const float* __restrict__ simc,
                                              float* __restrict__ topv, int* __restrict__ topi,
                                              float* __restrict__ exps, int row0) {
  __shared__ float vals[NROWS];
  __shared__ u64 wmax[4];
  __shared__ float outv[KSEL];
  __shared__ int outi[KSEL];
  const int row = row0 + blockIdx.x;
  const int t = threadIdx.x;
  const float* src = simc + (size_t)blockIdx.x * NROWS;
  for (int i = t; i < NROWS; i += 256) vals[i] = src[i];
  __syncthreads();

  auto mkkey = [](float v, int i) -> u64 {
    unsigned u = __float_as_uint(v);
    u = ((int)u < 0) ? ~u : (u | 0x80000000u);
    return ((u64)u << 32) | (u64)(0xFFFFFFFFu - (unsigned)i);
  };

  u64 lk = 0;
#pragma unroll
  for (int m = 0; m < 32; ++m) {
    int i = t + 256 * m;
    lk = umax64(lk, mkkey(vals[i], i));
  }

  const int lane = t & 63, wv = t >> 6;
  for (int it = 0; it < KSEL; ++it) {
    u64 wk = lk;
#pragma unroll
    for (int s = 32; s > 0; s >>= 1) {
      u64 o = __shfl_xor(wk, s);
      wk = umax64(wk, o);
    }
    if (lane == 0) wmax[wv] = wk;
    __syncthreads();
    u64 g = umax64(umax64(wmax[0], wmax[1]), umax64(wmax[2], wmax[3]));
    const unsigned ui = (unsigned)(g >> 32);
    const float v = __uint_as_float((ui & 0x80000000u) ? (ui ^ 0x80000000u) : ~ui);
    const int idx = (int)(0xFFFFFFFFu - (unsigned)(g & 0xFFFFFFFFull));
    if (t == 0) { outv[it] = v; outi[it] = idx; }
    if (t == (idx & 255)) {
      vals[idx] = -INFINITY;
      u64 nl = 0;
#pragma unroll
      for (int m = 0; m < 32; ++m) {
        int i = t + 256 * m;
        nl = umax64(nl, mkkey(vals[i], i));
      }
      lk = nl;
    }
    __syncthreads();
  }
  if (t < KSEL) {
    topv[(size_t)row * KSEL + t] = outv[t];
    topi[(size_t)row * KSEL + t] = outi[t];
  }
  if (t == 0) {
    float s = 0.f;
#pragma unroll
    for (int q = 0; q < 10; ++q) s += outv[q];
    exps[row] = expf(s / 40.0f);
  }
}

// ---------------- K3: adjacency build (sparse intersection) + row softmax ----------------
__global__ __launch_bounds__(256) void k_adj(const int* __restrict__ indexes,
                                             const float* __restrict__ topv, const int* __restrict__ topi,
                                             const float* __restrict__ exps, float* __restrict__ adj) {
  __shared__ int nbr[64];
  __shared__ int neigh[64][10];
  __shared__ float tv[64][10];
  __shared__ float adjL[64][64];
  const int b = blockIdx.x;
  const int t = threadIdx.x;
  const int idx = indexes[b];
  if (t < 64) nbr[t] = topi[(size_t)idx * KSEL + t];
  __syncthreads();
  for (int p = t; p < 640; p += 256) {
    const int r = p / 10, q = p - r * 10;
    const int m = nbr[r];
    const int c = topi[(size_t)m * KSEL + q];
    neigh[r][q] = c;
    tv[r][q] = topv[(size_t)m * KSEL + q] * exps[c];
  }
  __syncthreads();
  for (int p = t; p < 4096; p += 256) {
    const int i = p >> 6, j = p & 63;
    float s = 0.f;
#pragma unroll
    for (int q = 0; q < 10; ++q) {
      const int c = neigh[i][q];
      float add = 0.f;
      for (int s2 = 0; s2 < 10; ++s2) {
        if (neigh[j][s2] == c) { add = (tv[j][s2] > 0.f) ? tv[i][q] : 0.f; break; }
      }
      s += add;
    }
    adjL[i][j] = s;
  }
  __syncthreads();
  const int wv = t >> 6, lane = t & 63;
  for (int i = wv * 16; i < wv * 16 + 16; ++i) {
    float v = adjL[i][lane];
    float mx = v;
#pragma unroll
    for (int s = 32; s > 0; s >>= 1) mx = fmaxf(mx, __shfl_xor(mx, s));
    float e = expf(v - mx);
    float sum = e;
#pragma unroll
    for (int s = 32; s > 0; s >>= 1) sum += __shfl_xor(sum, s);
    adj[((size_t)b * 64 + i) * 64 + lane] = e / sum;
  }
}

// ---------------- K4: xs[b,r,:] = F[nbr] - F[nbr0] ----------------
__global__ void k_xs(const int* __restrict__ indexes, const int* __restrict__ topi,
                     const float* __restrict__ F, float* __restrict__ xs) {
  const int b = blockIdx.y, r = blockIdx.x;
  const int t = threadIdx.x;
  const int idx = indexes[b];
  const int m  = topi[(size_t)idx * KSEL + r];
  const int m0 = topi[(size_t)idx * KSEL + 0];
  const float4* pa = (const float4*)(F + (size_t)m * DFEAT);
  const float4* pb = (const float4*)(F + (size_t)m0 * DFEAT);
  float4* po = (float4*)(xs + ((size_t)b * 64 + r) * DFEAT);
  for (int i = t; i < DFEAT / 4; i += 256) {
    float4 a = pa[i], c = pb[i];
    po[i] = make_float4(a.x - c.x, a.y - c.y, a.z - c.z, a.w - c.w);
  }
}

// ---------------- K5: agg[b] = adj[b] @ X[b]  (64x64 @ 64xD) ----------------
__global__ __launch_bounds__(256) void k_agg(const float* __restrict__ adj, const float* __restrict__ X,
                                             float* __restrict__ out, int Dd) {
  __shared__ float adjL[4096];
  const int b = blockIdx.y;
  const int c = blockIdx.x * 256 + threadIdx.x;
  for (int i = threadIdx.x; i < 4096; i += 256) adjL[i] = adj[(size_t)b * 4096 + i];
  __syncthreads();
  const float* Xb = X + (size_t)b * 64 * Dd;
  float accv[64];
#pragma unroll
  for (int r = 0; r < 64; ++r) accv[r] = 0.f;
  for (int j0 = 0; j0 < 64; j0 += 4) {
    float x0 = Xb[(size_t)(j0 + 0) * Dd + c];
    float x1 = Xb[(size_t)(j0 + 1) * Dd + c];
    float x2 = Xb[(size_t)(j0 + 2) * Dd + c];
    float x3 = Xb[(size_t)(j0 + 3) * Dd + c];
#pragma unroll
    for (int r = 0; r < 64; ++r) {
      const float4 a = *(const float4*)&adjL[r * 64 + j0];
      accv[r] += a.x * x0 + a.y * x1 + a.z * x2 + a.w * x3;
    }
  }
  float* Ob = out + (size_t)b * 64 * Dd;
  for (int r = 0; r < 64; ++r) Ob[(size_t)r * Dd + c] = accv[r];
}

// ---------------- K6: H = act( [X1 | X2] @ W + bias ), M=4096 fixed ----------------
// act: 0 = relu, 1 = prelu(per-channel)
__global__ __launch_bounds__(256) void k_gemmcat(const float* __restrict__ X1, const float* __restrict__ X2,
                                                 int D1, int Ktot,
                                                 const float* __restrict__ W, const float* __restrict__ bias,
                                                 const float* __restrict__ prelu, float* __restrict__ out,
                                                 int Fdim, int act) {
  __shared__ float As[16][136];
  __shared__ float Bs[16][136];
  const int bf = blockIdx.x, bm = blockIdx.y;
  const int t = threadIdx.x;
  const int tx = t & 15, ty = t >> 4;
  float acc[8][8];
#pragma unroll
  for (int i = 0; i < 8; ++i)
#pragma unroll
    for (int j = 0; j < 8; ++j) acc[i][j] = 0.f;
  const int lr = t >> 1;
  const int lc2 = (t & 1) * 2;

  for (int k0 = 0; k0 < Ktot; k0 += 16) {
    __syncthreads();
    const float* Xp; int Dl, kk;
    if (k0 < D1) { Xp = X1; Dl = D1; kk = k0; }
    else         { Xp = X2; Dl = Ktot - D1; kk = k0 - D1; }
#pragma unroll
    for (int q = 0; q < 2; ++q) {
      const int c4 = lc2 + q;
      float4 v = *(const float4*)(Xp + (size_t)(bm*128 + lr) * Dl + kk + c4 * 4);
      As[c4*4+0][lr] = v.x; As[c4*4+1][lr] = v.y; As[c4*4+2][lr] = v.z; As[c4*4+3][lr] = v.w;
    }
#pragma unroll
    for (int q = 0; q < 2; ++q) {
      const int li = t * 2 + q;
      const int r16 = li >> 5, c4 = li & 31;
      float4 v = *(const float4*)(W + (size_t)(k0 + r16) * Fdim + bf*128 + c4 * 4);
      *(float4*)&Bs[r16][c4*4] = v;
    }
    __syncthreads();
#pragma unroll
    for (int k = 0; k < 16; ++k) {
      float4 a0 = *(const float4*)&As[k][ty*4];
      float4 a1 = *(const float4*)&As[k][64 + ty*4];
      float4 b0 = *(const float4*)&Bs[k][tx*4];
      float4 b1 = *(const float4*)&Bs[k][64 + tx*4];
      float ar[8] = {a0.x, a0.y, a0.z, a0.w, a1.x, a1.y, a1.z, a1.w};
      float br[8] = {b0.x, b0.y, b0.z, b0.w, b1.x, b1.y, b1.z, b1.w};
#pragma unroll
      for (int i = 0; i < 8; ++i)
#pragma unroll
        for (int j = 0; j < 8; ++j) acc[i][j] += ar[i] * br[j];
    }
  }

  const float* bp = bias + bf*128;
  float4 bb0 = *(const float4*)(bp + tx*4);
  float4 bb1 = *(const float4*)(bp + 64 + tx*4);
  float pa0[4] = {0.f,0.f,0.f,0.f}, pa1[4] = {0.f,0.f,0.f,0.f};
  if (act == 1) {
    const float* pp = prelu + bf*128;
    float4 q0 = *(const float4*)(pp + tx*4);
    float4 q1 = *(const float4*)(pp + 64 + tx*4);
    pa0[0]=q0.x; pa0[1]=q0.y; pa0[2]=q0.z; pa0[3]=q0.w;
    pa1[0]=q1.x; pa1[1]=q1.y; pa1[2]=q1.z; pa1[3]=q1.w;
  }
#pragma unroll
  for (int i = 0; i < 8; ++i) {
    const int gm = bm*128 + ((i < 4) ? (ty*4 + i) : (64 + ty*4 + (i - 4)));
    float o[8] = {acc[i][0]+bb0.x, acc[i][1]+bb0.y, acc[i][2]+bb0.z, acc[i][3]+bb0.w,
                  acc[i][4]+bb1.x, acc[i][5]+bb1.y, acc[i][6]+bb1.z, acc[i][7]+bb1.w};
    if (act == 0) {
#pragma unroll
      for (int j = 0; j < 8; ++j) o[j] = fmaxf(o[j], 0.f);
    } else {
#pragma unroll
      for (int j = 0; j < 4; ++j) o[j] = (o[j] > 0.f) ? o[j] : pa0[j] * o[j];
#pragma unroll
      for (int j = 0; j < 4; ++j) o[4+j] = (o[4+j] > 0.f) ? o[4+j] : pa1[j] * o[4+j];
    }
    float4 w0 = make_float4(o[0], o[1], o[2], o[3]);
    float4 w1 = make_float4(o[4], o[5], o[6], o[7]);
    *(float4*)(out + (size_t)gm * Fdim + bf*128 + tx*4) = w0;
    *(float4*)(out + (size_t)gm * Fdim + bf*128 + 64 + tx*4) = w1;
  }
}

// ---------------- K7: pred = HC @ Wc2 + bc2  (4096x256 @ 256x2) ----------------
__global__ __launch_bounds__(256) void k_final(const float* __restrict__ Hc, const float* __restrict__ Wc2,
                                               const float* __restrict__ bc2, float* __restrict__ outp) {
  __shared__ float w[512];
  __shared__ float red[512];
  const int t = threadIdx.x;
  for (int i = t; i < 512; i += 256) w[i] = Wc2[i];
  __syncthreads();
  const int m = blockIdx.x * 64 + (t >> 2);
  const int p = t & 3;
  const float* h = Hc + (size_t)m * 256;
  float s0 = 0.f, s1 = 0.f;
  for (int k = p * 64; k < p * 64 + 64; ++k) {
    float hv = h[k];
    s0 += hv * w[k * 2];
    s1 += hv * w[k * 2 + 1];
  }
  red[t * 2] = s0; red[t * 2 + 1] = s1;
  __syncthreads();
  if (p == 0) {
    for (int q = 1; q < 4; ++q) { s0 += red[(t + q) * 2]; s1 += red[(t + q) * 2 + 1]; }
    outp[m * 2 + 0] = s0 + bc2[0];
    outp[m * 2 + 1] = s1 + bc2[1];
  }
}

extern "C" void kernel_launch(void* const* d_in, const int* in_sizes, int n_in,
                              void* d_out, int out_size, void* d_ws, size_t ws_size,
                              hipStream_t stream) {
  const int*   indexes = (const int*)d_in[0];
  const float* F   = (const float*)d_in[1];
  // d_in[2]=labels, d_in[3]=domain: unused
  const float* W1  = (const float*)d_in[4];
  const float* b1  = (const float*)d_in[5];
  const float* W2  = (const float*)d_in[6];
  const float* b2  = (const float*)d_in[7];
  const float* W3  = (const float*)d_in[8];
  const float* b3  = (const float*)d_in[9];
  const float* W4  = (const float*)d_in[10];
  const float* b4  = (const float*)d_in[11];
  const float* Wc1 = (const float*)d_in[12];
  const float* bc1 = (const float*)d_in[13];
  const float* pre = (const float*)d_in[14];
  const float* Wc2 = (const float*)d_in[15];
  const float* bc2 = (const float*)d_in[16];
  float* out = (float*)d_out;

  // ---- workspace layout (adaptive; peak ~85 MB) ----
  size_t off = 0;
  auto take = [&](size_t bytes) -> char* {
    char* q = (char*)d_ws + off;
    off += (bytes + 255) & ~(size_t)255;
    return q;
  };
  float* TOPV = (float*)take((size_t)NROWS * KSEL * 4);   // 2 MB
  int*   TOPI = (int*)  take((size_t)NROWS * KSEL * 4);   // 2 MB
  float* EXPS = (float*)take((size_t)NROWS * 4);          // 32 KB
  float* ADJ  = (float*)take((size_t)64 * 64 * 64 * 4);   // 1 MB
  char*  big  = (char*)d_ws + off;
  const size_t big_bytes = (ws_size > off) ? (ws_size - off) : 0;

  // phase-B layout inside big (XS dead after layer-1 gemm; aliased by H2/H3/H4/HC)
  const size_t MB = 1024 * 1024;
  if (big_bytes < 80 * MB) {
    // insufficient workspace: emit zeros (distinct absmax signature) instead of faulting
    hipMemsetAsync(d_out, 0, (size_t)out_size * 4, stream);
    return;
  }
  float* XS  = (float*)(big);            // 32 MB  [4096 x 2048]
  float* AGG = (float*)(big + 32 * MB);  // 32 MB  [4096 x <=2048]
  float* H1  = (float*)(big + 64 * MB);  // 16 MB  [4096 x 1024]
  float* H2  = (float*)(big);            //  8 MB  (alias XS)
  float* H3  = (float*)(big +  8 * MB);  //  4 MB
  float* H4  = (float*)(big + 12 * MB);  //  4 MB
  float* HC  = (float*)(big + 16 * MB);  //  4 MB
  float* SIMC = (float*)(big);           // phase A: chunk x 8192 panel (<= 64 MB)

  // ---- phase A: chunked sim panel + top-k ----
  int chunk = 2048;
  while ((size_t)chunk * NROWS * 4 > big_bytes && chunk > 128) chunk >>= 1;
  for (int r0 = 0; r0 < NROWS; r0 += chunk) {
    k_simgemm_rows<<<dim3(64, chunk / 128), 256, 0, stream>>>(F, SIMC, r0);
    k_topk<<<chunk, 256, 0, stream>>>(SIMC, TOPV, TOPI, EXPS, r0);
  }

  // ---- phase B: graphs + layers ----
  k_adj<<<64, 256, 0, stream>>>(indexes, TOPV, TOPI, EXPS, ADJ);
  k_xs<<<dim3(64, 64), 256, 0, stream>>>(indexes, TOPI, F, XS);

  // layer 1: cat[xs, adj@xs] @ W1 (4096x1024) + relu
  k_agg<<<dim3(8, 64), 256, 0, stream>>>(ADJ, XS, AGG, 2048);
  k_gemmcat<<<dim3(8, 32), 256, 0, stream>>>(XS, AGG, 2048, 4096, W1, b1, nullptr, H1, 1024, 0);
  // layer 2
  k_agg<<<dim3(4, 64), 256, 0, stream>>>(ADJ, H1, AGG, 1024);
  k_gemmcat<<<dim3(4, 32), 256, 0, stream>>>(H1, AGG, 1024, 2048, W2, b2, nullptr, H2, 512, 0);
  // layer 3
  k_agg<<<dim3(2, 64), 256, 0, stream>>>(ADJ, H2, AGG, 512);
  k_gemmcat<<<dim3(2, 32), 256, 0, stream>>>(H2, AGG, 512, 1024, W3, b3, nullptr, H3, 256, 0);
  // layer 4
  k_agg<<<dim3(1, 64), 256, 0, stream>>>(ADJ, H3, AGG, 256);
  k_gemmcat<<<dim3(2, 32), 256, 0, stream>>>(H3, AGG, 256, 512, W4, b4, nullptr, H4, 256, 0);
  // classifier: prelu(H4 @ Wc1 + bc1)
  k_gemmcat<<<dim3(2, 32), 256, 0, stream>>>(H4, nullptr, 256, 256, Wc1, bc1, pre, HC, 256, 1);
  // final: HC @ Wc2 + bc2
  k_final<<<64, 256, 0, stream>>>(HC, Wc2, bc2, out);
}

// Round 3
// 3420.571 us; speedup vs baseline: 1.4843x; 1.4843x over previous
//
#include <hip/hip_runtime.h>
#include <hip/hip_bf16.h>
#include <math.h>

#define NROWS 8192
#define DFEAT 2048
#define KSEL  64

typedef unsigned long long u64;
typedef __attribute__((ext_vector_type(8))) short bf16x8;
typedef __attribute__((ext_vector_type(4))) float f32x4;

__device__ __forceinline__ u64 umax64(u64 a, u64 b) { return a > b ? a : b; }

// ---------------- K0: 3-way bf16 split of F (exact to 2^-27) ----------------
__global__ __launch_bounds__(256) void k_split(const float* __restrict__ F, ushort* __restrict__ H,
                                               ushort* __restrict__ M, ushort* __restrict__ L) {
  const size_t i0 = ((size_t)blockIdx.x * 256 + threadIdx.x) * 4;
  float4 x = *(const float4*)(F + i0);
  float xs[4] = {x.x, x.y, x.z, x.w};
  ushort h[4], m[4], l[4];
#pragma unroll
  for (int c = 0; c < 4; ++c) {
    float v = xs[c];
    __hip_bfloat16 bh = __float2bfloat16(v);
    float r1 = v - __bfloat162float(bh);
    __hip_bfloat16 bm = __float2bfloat16(r1);
    float r2 = r1 - __bfloat162float(bm);
    __hip_bfloat16 bl = __float2bfloat16(r2);
    h[c] = *(ushort*)&bh; m[c] = *(ushort*)&bm; l[c] = *(ushort*)&bl;
  }
  ushort4 vh = {h[0], h[1], h[2], h[3]};
  ushort4 vm = {m[0], m[1], m[2], m[3]};
  ushort4 vl = {l[0], l[1], l[2], l[3]};
  *(ushort4*)(H + i0) = vh;
  *(ushort4*)(M + i0) = vm;
  *(ushort4*)(L + i0) = vl;
}

// ---------------- K1-fast: sim panel via MFMA bf16x6 ----------------
// C[bm*128 + 0..127 (panel-local), bj*128 + 0..127] = F[row0+..] . F[..]^T
__global__ __launch_bounds__(256) void k_simgemm_mfma(
    const ushort* __restrict__ FH, const ushort* __restrict__ FM, const ushort* __restrict__ FL,
    float* __restrict__ C, int row0) {
  __shared__ ushort lds[6 * 4096];  // 6 tiles [128][32] bf16 = 48 KB: A_hi,A_mid,A_lo,B_hi,B_mid,B_lo
  const int bj = blockIdx.x;
  const int bm = blockIdx.y;
  const int t = threadIdx.x;
  const int w = t >> 6, l = t & 63;
  const int arow0 = row0 + bm * 128;
  const int brow0 = bj * 128;
  const int segr = l >> 2;      // row within 16-row segment
  const int segq = l & 3;       // 8-elem k quad
  const int fl15 = l & 15, fq = l >> 4;
  const int wr = w >> 1, wc = w & 1;
  const int mb = wr * 64, nb = wc * 64;

  f32x4 acc[4][4];
#pragma unroll
  for (int i = 0; i < 4; ++i)
#pragma unroll
    for (int j = 0; j < 4; ++j) acc[i][j] = (f32x4){0.f, 0.f, 0.f, 0.f};

  for (int k0 = 0; k0 < DFEAT; k0 += 32) {
    __syncthreads();
    // stage 48 KB: 48 segments of 1 KB; wave w issues segments w*12 .. w*12+11
#pragma unroll
    for (int c = 0; c < 12; ++c) {
      const int cc = w * 12 + c;
      const int tt = cc >> 3;        // tile 0..5
      const int p = cc & 7;          // 1KB segment within tile (16 rows)
      const int rowbase = (tt < 3) ? arow0 : brow0;
      const int sp = (tt < 3) ? tt : (tt - 3);
      const ushort* sel = (sp == 0) ? FH : ((sp == 1) ? FM : FL);
      const ushort* g = sel + (size_t)(rowbase + p * 16 + segr) * DFEAT + (k0 + segq * 8);
      __builtin_amdgcn_global_load_lds((const __attribute__((address_space(1))) unsigned int*)g,
                                       (__attribute__((address_space(3))) unsigned int*)&lds[tt * 4096 + p * 512],
                                       16, 0, 0);
    }
    __syncthreads();

    bf16x8 af[3][4];
    bf16x8 bg[3][4];
    const int kcol = fq * 8;
#pragma unroll
    for (int i = 0; i < 3; ++i)
#pragma unroll
      for (int fm = 0; fm < 4; ++fm)
        af[i][fm] = *(const bf16x8*)&lds[i * 4096 + (mb + fm * 16 + fl15) * 32 + kcol];
#pragma unroll
    for (int j = 0; j < 3; ++j)
#pragma unroll
      for (int fn = 0; fn < 4; ++fn)
        bg[j][fn] = *(const bf16x8*)&lds[(3 + j) * 4096 + (nb + fn * 16 + fl15) * 32 + kcol];

#pragma unroll
    for (int fm = 0; fm < 4; ++fm)
#pragma unroll
      for (int fn = 0; fn < 4; ++fn) {
        f32x4 a = acc[fm][fn];
        a = __builtin_amdgcn_mfma_f32_16x16x32_bf16(af[0][fm], bg[0][fn], a, 0, 0, 0);
        a = __builtin_amdgcn_mfma_f32_16x16x32_bf16(af[1][fm], bg[0][fn], a, 0, 0, 0);
        a = __builtin_amdgcn_mfma_f32_16x16x32_bf16(af[0][fm], bg[1][fn], a, 0, 0, 0);
        a = __builtin_amdgcn_mfma_f32_16x16x32_bf16(af[2][fm], bg[0][fn], a, 0, 0, 0);
        a = __builtin_amdgcn_mfma_f32_16x16x32_bf16(af[0][fm], bg[2][fn], a, 0, 0, 0);
        a = __builtin_amdgcn_mfma_f32_16x16x32_bf16(af[1][fm], bg[1][fn], a, 0, 0, 0);
        acc[fm][fn] = a;
      }
  }

  // C/D layout: row = fq*4 + r, col = fl15 (within 16x16 frag)
#pragma unroll
  for (int fm = 0; fm < 4; ++fm) {
    const int lm = bm * 128 + mb + fm * 16 + fq * 4;
#pragma unroll
    for (int fn = 0; fn < 4; ++fn) {
      const int col = bj * 128 + nb + fn * 16 + fl15;
#pragma unroll
      for (int r = 0; r < 4; ++r)
        C[(size_t)(lm + r) * NROWS + col] = acc[fm][fn][r];
    }
  }
}

// ---------------- K1-fallback: f32 vector sim panel ----------------
__global__ __launch_bounds__(256) void k_simgemm_rows(const float* __restrict__ F, float* __restrict__ C,
                                                      int row0) {
  const int bj = blockIdx.x;
  const int bil = blockIdx.y;
  __shared__ float As[16][136];
  __shared__ float Bs[16][136];
  const int t = threadIdx.x;
  const int tx = t & 15, ty = t >> 4;
  float acc[8][8];
#pragma unroll
  for (int i = 0; i < 8; ++i)
#pragma unroll
    for (int j = 0; j < 8; ++j) acc[i][j] = 0.f;

  const int lr = t >> 1;
  const int lc2 = (t & 1) * 2;
  const float* Abase = F + ((size_t)row0 + (size_t)bil * 128) * DFEAT;
  const float* Bbase = F + (size_t)bj * 128 * DFEAT;

  for (int k0 = 0; k0 < DFEAT; k0 += 16) {
    __syncthreads();
#pragma unroll
    for (int q = 0; q < 2; ++q) {
      const int c4 = lc2 + q;
      float4 va = *(const float4*)(Abase + (size_t)lr * DFEAT + k0 + c4 * 4);
      float4 vb = *(const float4*)(Bbase + (size_t)lr * DFEAT + k0 + c4 * 4);
      As[c4*4+0][lr] = va.x; As[c4*4+1][lr] = va.y; As[c4*4+2][lr] = va.z; As[c4*4+3][lr] = va.w;
      Bs[c4*4+0][lr] = vb.x; Bs[c4*4+1][lr] = vb.y; Bs[c4*4+2][lr] = vb.z; Bs[c4*4+3][lr] = vb.w;
    }
    __syncthreads();
#pragma unroll
    for (int k = 0; k < 16; ++k) {
      float4 a0 = *(const float4*)&As[k][ty*4];
      float4 a1 = *(const float4*)&As[k][64 + ty*4];
      float4 b0 = *(const float4*)&Bs[k][tx*4];
      float4 b1 = *(const float4*)&Bs[k][64 + tx*4];
      float ar[8] = {a0.x, a0.y, a0.z, a0.w, a1.x, a1.y, a1.z, a1.w};
      float br[8] = {b0.x, b0.y, b0.z, b0.w, b1.x, b1.y, b1.z, b1.w};
#pragma unroll
      for (int i = 0; i < 8; ++i)
#pragma unroll
        for (int j = 0; j < 8; ++j) acc[i][j] += ar[i] * br[j];
    }
  }

#pragma unroll
  for (int i = 0; i < 8; ++i) {
    const int li = bil*128 + ((i < 4) ? (ty*4 + i) : (64 + ty*4 + (i - 4)));
    float4 v0 = make_float4(acc[i][0], acc[i][1], acc[i][2], acc[i][3]);
    float4 v1 = make_float4(acc[i][4], acc[i][5], acc[i][6], acc[i][7]);
    *(float4*)(C + (size_t)li * NROWS + bj*128 + tx*4) = v0;
    *(float4*)(C + (size_t)li * NROWS + bj*128 + 64 + tx*4) = v1;
  }
}

// ---------------- K2: top-64 per row + exp_sim ----------------
__global__ __launch_bounds__(256) void k_topk(const float* __restrict__ simc,
                                              float* __restrict__ topv, int* __restrict__ topi,
                                              float* __restrict__ exps, int row0) {
  __shared__ float vals[NROWS];
  __shared__ u64 wmax[4];
  __shared__ float outv[KSEL];
  __shared__ int outi[KSEL];
  const int row = row0 + blockIdx.x;
  const int t = threadIdx.x;
  const float* src = simc + (size_t)blockIdx.x * NROWS;
  for (int i = t; i < NROWS; i += 256) vals[i] = src[i];
  __syncthreads();

  auto mkkey = [](float v, int i) -> u64 {
    unsigned u = __float_as_uint(v);
    u = ((int)u < 0) ? ~u : (u | 0x80000000u);
    return ((u64)u << 32) | (u64)(0xFFFFFFFFu - (unsigned)i);
  };

  u64 lk = 0;
#pragma unroll
  for (int m = 0; m < 32; ++m) {
    int i = t + 256 * m;
    lk = umax64(lk, mkkey(vals[i], i));
  }

  const int lane = t & 63, wv = t >> 6;
  for (int it = 0; it < KSEL; ++it) {
    u64 wk = lk;
#pragma unroll
    for (int s = 32; s > 0; s >>= 1) {
      u64 o = __shfl_xor(wk, s);
      wk = umax64(wk, o);
    }
    if (lane == 0) wmax[wv] = wk;
    __syncthreads();
    u64 g = umax64(umax64(wmax[0], wmax[1]), umax64(wmax[2], wmax[3]));
    const unsigned ui = (unsigned)(g >> 32);
    const float v = __uint_as_float((ui & 0x80000000u) ? (ui ^ 0x80000000u) : ~ui);
    const int idx = (int)(0xFFFFFFFFu - (unsigned)(g & 0xFFFFFFFFull));
    if (t == 0) { outv[it] = v; outi[it] = idx; }
    if (t == (idx & 255)) {
      vals[idx] = -INFINITY;
      u64 nl = 0;
#pragma unroll
      for (int m = 0; m < 32; ++m) {
        int i = t + 256 * m;
        nl = umax64(nl, mkkey(vals[i], i));
      }
      lk = nl;
    }
    __syncthreads();
  }
  if (t < KSEL) {
    topv[(size_t)row * KSEL + t] = outv[t];
    topi[(size_t)row * KSEL + t] = outi[t];
  }
  if (t == 0) {
    float s = 0.f;
#pragma unroll
    for (int q = 0; q < 10; ++q) s += outv[q];
    exps[row] = expf(s / 40.0f);
  }
}

// ---------------- K3: adjacency build + row softmax ----------------
__global__ __launch_bounds__(256) void k_adj(const int* __restrict__ indexes,
                                             const float* __restrict__ topv, const int* __restrict__ topi,
                                             const float* __restrict__ exps, float* __restrict__ adj) {
  __shared__ int nbr[64];
  __shared__ int neigh[64][10];
  __shared__ float tv[64][10];
  __shared__ float adjL[64][64];
  const int b = blockIdx.x;
  const int t = threadIdx.x;
  const int idx = indexes[b];
  if (t < 64) nbr[t] = topi[(size_t)idx * KSEL + t];
  __syncthreads();
  for (int p = t; p < 640; p += 256) {
    const int r = p / 10, q = p - r * 10;
    const int m = nbr[r];
    const int c = topi[(size_t)m * KSEL + q];
    neigh[r][q] = c;
    tv[r][q] = topv[(size_t)m * KSEL + q] * exps[c];
  }
  __syncthreads();
  for (int p = t; p < 4096; p += 256) {
    const int i = p >> 6, j = p & 63;
    float s = 0.f;
#pragma unroll
    for (int q = 0; q < 10; ++q) {
      const int c = neigh[i][q];
      float add = 0.f;
      for (int s2 = 0; s2 < 10; ++s2) {
        if (neigh[j][s2] == c) { add = (tv[j][s2] > 0.f) ? tv[i][q] : 0.f; break; }
      }
      s += add;
    }
    adjL[i][j] = s;
  }
  __syncthreads();
  const int wv = t >> 6, lane = t & 63;
  for (int i = wv * 16; i < wv * 16 + 16; ++i) {
    float v = adjL[i][lane];
    float mx = v;
#pragma unroll
    for (int s = 32; s > 0; s >>= 1) mx = fmaxf(mx, __shfl_xor(mx, s));
    float e = expf(v - mx);
    float sum = e;
#pragma unroll
    for (int s = 32; s > 0; s >>= 1) sum += __shfl_xor(sum, s);
    adj[((size_t)b * 64 + i) * 64 + lane] = e / sum;
  }
}

// ---------------- K4: xs[b,r,:] = F[nbr] - F[nbr0] ----------------
__global__ void k_xs(const int* __restrict__ indexes, const int* __restrict__ topi,
                     const float* __restrict__ F, float* __restrict__ xs) {
  const int b = blockIdx.y, r = blockIdx.x;
  const int t = threadIdx.x;
  const int idx = indexes[b];
  const int m  = topi[(size_t)idx * KSEL + r];
  const int m0 = topi[(size_t)idx * KSEL + 0];
  const float4* pa = (const float4*)(F + (size_t)m * DFEAT);
  const float4* pb = (const float4*)(F + (size_t)m0 * DFEAT);
  float4* po = (float4*)(xs + ((size_t)b * 64 + r) * DFEAT);
  for (int i = t; i < DFEAT / 4; i += 256) {
    float4 a = pa[i], c = pb[i];
    po[i] = make_float4(a.x - c.x, a.y - c.y, a.z - c.z, a.w - c.w);
  }
}

// ---------------- K5: agg[b] = adj[b] @ X[b] ----------------
__global__ __launch_bounds__(256) void k_agg(const float* __restrict__ adj, const float* __restrict__ X,
                                             float* __restrict__ out, int Dd) {
  __shared__ float adjL[4096];
  const int b = blockIdx.y;
  const int c = blockIdx.x * 256 + threadIdx.x;
  for (int i = threadIdx.x; i < 4096; i += 256) adjL[i] = adj[(size_t)b * 4096 + i];
  __syncthreads();
  const float* Xb = X + (size_t)b * 64 * Dd;
  float accv[64];
#pragma unroll
  for (int r = 0; r < 64; ++r) accv[r] = 0.f;
  for (int j0 = 0; j0 < 64; j0 += 4) {
    float x0 = Xb[(size_t)(j0 + 0) * Dd + c];
    float x1 = Xb[(size_t)(j0 + 1) * Dd + c];
    float x2 = Xb[(size_t)(j0 + 2) * Dd + c];
    float x3 = Xb[(size_t)(j0 + 3) * Dd + c];
#pragma unroll
    for (int r = 0; r < 64; ++r) {
      const float4 a = *(const float4*)&adjL[r * 64 + j0];
      accv[r] += a.x * x0 + a.y * x1 + a.z * x2 + a.w * x3;
    }
  }
  float* Ob = out + (size_t)b * 64 * Dd;
  for (int r = 0; r < 64; ++r) Ob[(size_t)r * Dd + c] = accv[r];
}

// ---------------- K6: H = act( [X1 | X2] @ W + bias ) ----------------
__global__ __launch_bounds__(256) void k_gemmcat(const float* __restrict__ X1, const float* __restrict__ X2,
                                                 int D1, int Ktot,
                                                 const float* __restrict__ W, const float* __restrict__ bias,
                                                 const float* __restrict__ prelu, float* __restrict__ out,
                                                 int Fdim, int act) {
  __shared__ float As[16][136];
  __shared__ float Bs[16][136];
  const int bf = blockIdx.x, bm = blockIdx.y;
  const int t = threadIdx.x;
  const int tx = t & 15, ty = t >> 4;
  float acc[8][8];
#pragma unroll
  for (int i = 0; i < 8; ++i)
#pragma unroll
    for (int j = 0; j < 8; ++j) acc[i][j] = 0.f;
  const int lr = t >> 1;
  const int lc2 = (t & 1) * 2;

  for (int k0 = 0; k0 < Ktot; k0 += 16) {
    __syncthreads();
    const float* Xp; int Dl, kk;
    if (k0 < D1) { Xp = X1; Dl = D1; kk = k0; }
    else         { Xp = X2; Dl = Ktot - D1; kk = k0 - D1; }
#pragma unroll
    for (int q = 0; q < 2; ++q) {
      const int c4 = lc2 + q;
      float4 v = *(const float4*)(Xp + (size_t)(bm*128 + lr) * Dl + kk + c4 * 4);
      As[c4*4+0][lr] = v.x; As[c4*4+1][lr] = v.y; As[c4*4+2][lr] = v.z; As[c4*4+3][lr] = v.w;
    }
#pragma unroll
    for (int q = 0; q < 2; ++q) {
      const int li = t * 2 + q;
      const int r16 = li >> 5, c4 = li & 31;
      float4 v = *(const float4*)(W + (size_t)(k0 + r16) * Fdim + bf*128 + c4 * 4);
      *(float4*)&Bs[r16][c4*4] = v;
    }
    __syncthreads();
#pragma unroll
    for (int k = 0; k < 16; ++k) {
      float4 a0 = *(const float4*)&As[k][ty*4];
      float4 a1 = *(const float4*)&As[k][64 + ty*4];
      float4 b0 = *(const float4*)&Bs[k][tx*4];
      float4 b1 = *(const float4*)&Bs[k][64 + tx*4];
      float ar[8] = {a0.x, a0.y, a0.z, a0.w, a1.x, a1.y, a1.z, a1.w};
      float br[8] = {b0.x, b0.y, b0.z, b0.w, b1.x, b1.y, b1.z, b1.w};
#pragma unroll
      for (int i = 0; i < 8; ++i)
#pragma unroll
        for (int j = 0; j < 8; ++j) acc[i][j] += ar[i] * br[j];
    }
  }

  const float* bp = bias + bf*128;
  float4 bb0 = *(const float4*)(bp + tx*4);
  float4 bb1 = *(const float4*)(bp + 64 + tx*4);
  float pa0[4] = {0.f,0.f,0.f,0.f}, pa1[4] = {0.f,0.f,0.f,0.f};
  if (act == 1) {
    const float* pp = prelu + bf*128;
    float4 q0 = *(const float4*)(pp + tx*4);
    float4 q1 = *(const float4*)(pp + 64 + tx*4);
    pa0[0]=q0.x; pa0[1]=q0.y; pa0[2]=q0.z; pa0[3]=q0.w;
    pa1[0]=q1.x; pa1[1]=q1.y; pa1[2]=q1.z; pa1[3]=q1.w;
  }
#pragma unroll
  for (int i = 0; i < 8; ++i) {
    const int gm = bm*128 + ((i < 4) ? (ty*4 + i) : (64 + ty*4 + (i - 4)));
    float o[8] = {acc[i][0]+bb0.x, acc[i][1]+bb0.y, acc[i][2]+bb0.z, acc[i][3]+bb0.w,
                  acc[i][4]+bb1.x, acc[i][5]+bb1.y, acc[i][6]+bb1.z, acc[i][7]+bb1.w};
    if (act == 0) {
#pragma unroll
      for (int j = 0; j < 8; ++j) o[j] = fmaxf(o[j], 0.f);
    } else {
#pragma unroll
      for (int j = 0; j < 4; ++j) o[j] = (o[j] > 0.f) ? o[j] : pa0[j] * o[j];
#pragma unroll
      for (int j = 0; j < 4; ++j) o[4+j] = (o[4+j] > 0.f) ? o[4+j] : pa1[j] * o[4+j];
    }
    float4 w0 = make_float4(o[0], o[1], o[2], o[3]);
    float4 w1 = make_float4(o[4], o[5], o[6], o[7]);
    *(float4*)(out + (size_t)gm * Fdim + bf*128 + tx*4) = w0;
    *(float4*)(out + (size_t)gm * Fdim + bf*128 + 64 + tx*4) = w1;
  }
}

// ---------------- K7: pred = HC @ Wc2 + bc2 ----------------
__global__ __launch_bounds__(256) void k_final(const float* __restrict__ Hc, const float* __restrict__ Wc2,
                                               const float* __restrict__ bc2, float* __restrict__ outp) {
  __shared__ float w[512];
  __shared__ float red[512];
  const int t = threadIdx.x;
  for (int i = t; i < 512; i += 256) w[i] = Wc2[i];
  __syncthreads();
  const int m = blockIdx.x * 64 + (t >> 2);
  const int p = t & 3;
  const float* h = Hc + (size_t)m * 256;
  float s0 = 0.f, s1 = 0.f;
  for (int k = p * 64; k < p * 64 + 64; ++k) {
    float hv = h[k];
    s0 += hv * w[k * 2];
    s1 += hv * w[k * 2 + 1];
  }
  red[t * 2] = s0; red[t * 2 + 1] = s1;
  __syncthreads();
  if (p == 0) {
    for (int q = 1; q < 4; ++q) { s0 += red[(t + q) * 2]; s1 += red[(t + q) * 2 + 1]; }
    outp[m * 2 + 0] = s0 + bc2[0];
    outp[m * 2 + 1] = s1 + bc2[1];
  }
}

extern "C" void kernel_launch(void* const* d_in, const int* in_sizes, int n_in,
                              void* d_out, int out_size, void* d_ws, size_t ws_size,
                              hipStream_t stream) {
  const int*   indexes = (const int*)d_in[0];
  const float* F   = (const float*)d_in[1];
  const float* W1  = (const float*)d_in[4];
  const float* b1  = (const float*)d_in[5];
  const float* W2  = (const float*)d_in[6];
  const float* b2  = (const float*)d_in[7];
  const float* W3  = (const float*)d_in[8];
  const float* b3  = (const float*)d_in[9];
  const float* W4  = (const float*)d_in[10];
  const float* b4  = (const float*)d_in[11];
  const float* Wc1 = (const float*)d_in[12];
  const float* bc1 = (const float*)d_in[13];
  const float* pre = (const float*)d_in[14];
  const float* Wc2 = (const float*)d_in[15];
  const float* bc2 = (const float*)d_in[16];
  float* out = (float*)d_out;

  // ---- fixed workspace ----
  size_t off = 0;
  auto take = [&](size_t bytes) -> char* {
    char* q = (char*)d_ws + off;
    off += (bytes + 255) & ~(size_t)255;
    return q;
  };
  float* TOPV = (float*)take((size_t)NROWS * KSEL * 4);
  int*   TOPI = (int*)  take((size_t)NROWS * KSEL * 4);
  float* EXPS = (float*)take((size_t)NROWS * 4);
  float* ADJ  = (float*)take((size_t)64 * 64 * 64 * 4);
  const size_t offA = off;
  char*  big  = (char*)d_ws + offA;
  const size_t big_bytes = (ws_size > offA) ? (ws_size - offA) : 0;

  const size_t MB = 1024 * 1024;
  if (big_bytes < 80 * MB) {
    hipMemsetAsync(d_out, 0, (size_t)out_size * 4, stream);
    return;
  }

  // ---- phase A: sim + top-k ----
  const size_t splitBytes = (size_t)NROWS * DFEAT * 2;   // 33.5 MB per split
  int fchunk = 0;
  for (int c = 2048; c >= 512; c >>= 1) {
    if (offA + 3 * splitBytes + (size_t)c * NROWS * 4 <= ws_size) { fchunk = c; break; }
  }

  if (fchunk > 0) {
    // fast path: bf16x6 MFMA
    ushort* FH = (ushort*)big;
    ushort* FM = (ushort*)(big + splitBytes);
    ushort* FL = (ushort*)(big + 2 * splitBytes);
    float* SIMC = (float*)(big + 3 * splitBytes);
    k_split<<<NROWS * DFEAT / 1024, 256, 0, stream>>>(F, FH, FM, FL);
    for (int r0 = 0; r0 < NROWS; r0 += fchunk) {
      k_simgemm_mfma<<<dim3(64, fchunk / 128), 256, 0, stream>>>(FH, FM, FL, SIMC, r0);
      k_topk<<<fchunk, 256, 0, stream>>>(SIMC, TOPV, TOPI, EXPS, r0);
    }
  } else {
    // fallback: f32 vector path (round-2 behavior)
    float* SIMC = (float*)big;
    int chunk = 2048;
    while ((size_t)chunk * NROWS * 4 > big_bytes && chunk > 128) chunk >>= 1;
    for (int r0 = 0; r0 < NROWS; r0 += chunk) {
      k_simgemm_rows<<<dim3(64, chunk / 128), 256, 0, stream>>>(F, SIMC, r0);
      k_topk<<<chunk, 256, 0, stream>>>(SIMC, TOPV, TOPI, EXPS, r0);
    }
  }

  // ---- phase B: graphs + layers (aliases the phase-A region; all phase-A data dead) ----
  float* XS  = (float*)(big);
  float* AGG = (float*)(big + 32 * MB);
  float* H1  = (float*)(big + 64 * MB);
  float* H2  = (float*)(big);            // alias XS (dead after layer-1 gemm)
  float* H3  = (float*)(big +  8 * MB);
  float* H4  = (float*)(big + 12 * MB);
  float* HC  = (float*)(big + 16 * MB);

  k_adj<<<64, 256, 0, stream>>>(indexes, TOPV, TOPI, EXPS, ADJ);
  k_xs<<<dim3(64, 64), 256, 0, stream>>>(indexes, TOPI, F, XS);

  k_agg<<<dim3(8, 64), 256, 0, stream>>>(ADJ, XS, AGG, 2048);
  k_gemmcat<<<dim3(8, 32), 256, 0, stream>>>(XS, AGG, 2048, 4096, W1, b1, nullptr, H1, 1024, 0);
  k_agg<<<dim3(4, 64), 256, 0, stream>>>(ADJ, H1, AGG, 1024);
  k_gemmcat<<<dim3(4, 32), 256, 0, stream>>>(H1, AGG, 1024, 2048, W2, b2, nullptr, H2, 512, 0);
  k_agg<<<dim3(2, 64), 256, 0, stream>>>(ADJ, H2, AGG, 512);
  k_gemmcat<<<dim3(2, 32), 256, 0, stream>>>(H2, AGG, 512, 1024, W3, b3, nullptr, H3, 256, 0);
  k_agg<<<dim3(1, 64), 256, 0, stream>>>(ADJ, H3, AGG, 256);
  k_gemmcat<<<dim3(2, 32), 256, 0, stream>>>(H3, AGG, 256, 512, W4, b4, nullptr, H4, 256, 0);
  k_gemmcat<<<dim3(2, 32), 256, 0, stream>>>(H4, nullptr, 256, 256, Wc1, bc1, pre, HC, 256, 1);
  k_final<<<64, 256, 0, stream>>>(HC, Wc2, bc2, out);
}

// Round 5
// 2572.671 us; speedup vs baseline: 1.9735x; 1.3296x over previous
//
#include <hip/hip_runtime.h>
#include <hip/hip_bf16.h>
#include <math.h>

#define NROWS 8192
#define DFEAT 2048
#define KSEL  64

typedef unsigned long long u64;
typedef __attribute__((ext_vector_type(8))) short bf16x8;
typedef __attribute__((ext_vector_type(4))) float f32x4;

__device__ __forceinline__ u64 umax64(u64 a, u64 b) { return a > b ? a : b; }

__device__ __forceinline__ void split2(float v, ushort& h, ushort& l) {
  __hip_bfloat16 bh = __float2bfloat16(v);
  float r = v - __bfloat162float(bh);
  __hip_bfloat16 bl = __float2bfloat16(r);
  h = *(ushort*)&bh; l = *(ushort*)&bl;
}

// ---------------- K0: 3-way bf16 split of F (exact to 2^-27) ----------------
__global__ __launch_bounds__(256) void k_split(const float* __restrict__ F, ushort* __restrict__ H,
                                               ushort* __restrict__ M, ushort* __restrict__ L) {
  const size_t i0 = ((size_t)blockIdx.x * 256 + threadIdx.x) * 4;
  float4 x = *(const float4*)(F + i0);
  float xs[4] = {x.x, x.y, x.z, x.w};
  ushort h[4], m[4], l[4];
#pragma unroll
  for (int c = 0; c < 4; ++c) {
    float v = xs[c];
    __hip_bfloat16 bh = __float2bfloat16(v);
    float r1 = v - __bfloat162float(bh);
    __hip_bfloat16 bm = __float2bfloat16(r1);
    float r2 = r1 - __bfloat162float(bm);
    __hip_bfloat16 bl = __float2bfloat16(r2);
    h[c] = *(ushort*)&bh; m[c] = *(ushort*)&bm; l[c] = *(ushort*)&bl;
  }
  ushort4 vh = {h[0], h[1], h[2], h[3]};
  ushort4 vm = {m[0], m[1], m[2], m[3]};
  ushort4 vl = {l[0], l[1], l[2], l[3]};
  *(ushort4*)(H + i0) = vh;
  *(ushort4*)(M + i0) = vm;
  *(ushort4*)(L + i0) = vl;
}

// ---------------- K1: sim panel via MFMA bf16x6 (proven; unchanged) ----------------
__global__ __launch_bounds__(256) void k_simgemm_mfma(
    const ushort* __restrict__ FH, const ushort* __restrict__ FM, const ushort* __restrict__ FL,
    float* __restrict__ C, int row0) {
  __shared__ ushort lds[6 * 4096];
  const int bj = blockIdx.x;
  const int bm = blockIdx.y;
  const int t = threadIdx.x;
  const int w = t >> 6, l = t & 63;
  const int arow0 = row0 + bm * 128;
  const int brow0 = bj * 128;
  const int segr = l >> 2;
  const int segq = l & 3;
  const int fl15 = l & 15, fq = l >> 4;
  const int wr = w >> 1, wc = w & 1;
  const int mb = wr * 64, nb = wc * 64;

  f32x4 acc[4][4];
#pragma unroll
  for (int i = 0; i < 4; ++i)
#pragma unroll
    for (int j = 0; j < 4; ++j) acc[i][j] = (f32x4){0.f, 0.f, 0.f, 0.f};

  for (int k0 = 0; k0 < DFEAT; k0 += 32) {
    __syncthreads();
#pragma unroll
    for (int c = 0; c < 12; ++c) {
      const int cc = w * 12 + c;
      const int tt = cc >> 3;
      const int p = cc & 7;
      const int rowbase = (tt < 3) ? arow0 : brow0;
      const int sp = (tt < 3) ? tt : (tt - 3);
      const ushort* sel = (sp == 0) ? FH : ((sp == 1) ? FM : FL);
      const ushort* g = sel + (size_t)(rowbase + p * 16 + segr) * DFEAT + (k0 + segq * 8);
      __builtin_amdgcn_global_load_lds((const __attribute__((address_space(1))) unsigned int*)g,
                                       (__attribute__((address_space(3))) unsigned int*)&lds[tt * 4096 + p * 512],
                                       16, 0, 0);
    }
    __syncthreads();

    bf16x8 af[3][4];
    bf16x8 bg[3][4];
    const int kcol = fq * 8;
#pragma unroll
    for (int i = 0; i < 3; ++i)
#pragma unroll
      for (int fm = 0; fm < 4; ++fm)
        af[i][fm] = *(const bf16x8*)&lds[i * 4096 + (mb + fm * 16 + fl15) * 32 + kcol];
#pragma unroll
    for (int j = 0; j < 3; ++j)
#pragma unroll
      for (int fn = 0; fn < 4; ++fn)
        bg[j][fn] = *(const bf16x8*)&lds[(3 + j) * 4096 + (nb + fn * 16 + fl15) * 32 + kcol];

#pragma unroll
    for (int fm = 0; fm < 4; ++fm)
#pragma unroll
      for (int fn = 0; fn < 4; ++fn) {
        f32x4 a = acc[fm][fn];
        a = __builtin_amdgcn_mfma_f32_16x16x32_bf16(af[0][fm], bg[0][fn], a, 0, 0, 0);
        a = __builtin_amdgcn_mfma_f32_16x16x32_bf16(af[1][fm], bg[0][fn], a, 0, 0, 0);
        a = __builtin_amdgcn_mfma_f32_16x16x32_bf16(af[0][fm], bg[1][fn], a, 0, 0, 0);
        a = __builtin_amdgcn_mfma_f32_16x16x32_bf16(af[2][fm], bg[0][fn], a, 0, 0, 0);
        a = __builtin_amdgcn_mfma_f32_16x16x32_bf16(af[0][fm], bg[2][fn], a, 0, 0, 0);
        a = __builtin_amdgcn_mfma_f32_16x16x32_bf16(af[1][fm], bg[1][fn], a, 0, 0, 0);
        acc[fm][fn] = a;
      }
  }

#pragma unroll
  for (int fm = 0; fm < 4; ++fm) {
    const int lm = bm * 128 + mb + fm * 16 + fq * 4;
#pragma unroll
    for (int fn = 0; fn < 4; ++fn) {
      const int col = bj * 128 + nb + fn * 16 + fl15;
#pragma unroll
      for (int r = 0; r < 4; ++r)
        C[(size_t)(lm + r) * NROWS + col] = acc[fm][fn][r];
    }
  }
}

// ---------------- K1b: generic bf16x3 MFMA GEMM: C = A . B^T ----------------
__global__ __launch_bounds__(256) void k_gemm3(const ushort* __restrict__ AH, const ushort* __restrict__ AL,
                                               const ushort* __restrict__ BH, const ushort* __restrict__ BL,
                                               float* __restrict__ C, int K, int N) {
  __shared__ ushort lds[4 * 4096];
  const int bj = blockIdx.x, bm = blockIdx.y;
  const int t = threadIdx.x;
  const int w = t >> 6, l = t & 63;
  const int segr = l >> 2, segq = l & 3;
  const int fl15 = l & 15, fq = l >> 4;
  const int wr = w >> 1, wc = w & 1;
  const int mb = wr * 64, nb = wc * 64;

  f32x4 acc[4][4];
#pragma unroll
  for (int i = 0; i < 4; ++i)
#pragma unroll
    for (int j = 0; j < 4; ++j) acc[i][j] = (f32x4){0.f, 0.f, 0.f, 0.f};

  for (int k0 = 0; k0 < K; k0 += 32) {
    __syncthreads();
#pragma unroll
    for (int c = 0; c < 8; ++c) {
      const int s = w * 8 + c;
      const int tt = s >> 3;          // 0=AH 1=AL 2=BH 3=BL
      const int p = s & 7;
      const int rowbase = (tt < 2) ? (bm * 128) : (bj * 128);
      const ushort* sel = (tt == 0) ? AH : ((tt == 1) ? AL : ((tt == 2) ? BH : BL));
      const ushort* g = sel + (size_t)(rowbase + p * 16 + segr) * K + (k0 + segq * 8);
      __builtin_amdgcn_global_load_lds((const __attribute__((address_space(1))) unsigned int*)g,
                                       (__attribute__((address_space(3))) unsigned int*)&lds[s * 512],
                                       16, 0, 0);
    }
    __syncthreads();

    bf16x8 af[2][4];
    bf16x8 bg[2][4];
    const int kcol = fq * 8;
#pragma unroll
    for (int i = 0; i < 2; ++i)
#pragma unroll
      for (int fm = 0; fm < 4; ++fm)
        af[i][fm] = *(const bf16x8*)&lds[i * 4096 + (mb + fm * 16 + fl15) * 32 + kcol];
#pragma unroll
    for (int j = 0; j < 2; ++j)
#pragma unroll
      for (int fn = 0; fn < 4; ++fn)
        bg[j][fn] = *(const bf16x8*)&lds[(2 + j) * 4096 + (nb + fn * 16 + fl15) * 32 + kcol];

#pragma unroll
    for (int fm = 0; fm < 4; ++fm)
#pragma unroll
      for (int fn = 0; fn < 4; ++fn) {
        f32x4 a = acc[fm][fn];
        a = __builtin_amdgcn_mfma_f32_16x16x32_bf16(af[0][fm], bg[0][fn], a, 0, 0, 0);
        a = __builtin_amdgcn_mfma_f32_16x16x32_bf16(af[0][fm], bg[1][fn], a, 0, 0, 0);
        a = __builtin_amdgcn_mfma_f32_16x16x32_bf16(af[1][fm], bg[0][fn], a, 0, 0, 0);
        acc[fm][fn] = a;
      }
  }

#pragma unroll
  for (int fm = 0; fm < 4; ++fm) {
    const int row = bm * 128 + mb + fm * 16 + fq * 4;
#pragma unroll
    for (int fn = 0; fn < 4; ++fn) {
      const int col = bj * 128 + nb + fn * 16 + fl15;
#pragma unroll
      for (int r = 0; r < 4; ++r)
        C[(size_t)(row + r) * N + col] = acc[fm][fn][r];
    }
  }
}

// ---------------- K2: top-64 per row + exp_sim ----------------
__global__ __launch_bounds__(256) void k_topk(const float* __restrict__ simc,
                                              float* __restrict__ topv, int* __restrict__ topi,
                                              float* __restrict__ exps, int row0) {
  __shared__ float vals[NROWS];
  __shared__ u64 wmax[4];
  __shared__ float outv[KSEL];
  __shared__ int outi[KSEL];
  const int row = row0 + blockIdx.x;
  const int t = threadIdx.x;
  const float* src = simc + (size_t)blockIdx.x * NROWS;
  for (int i = t; i < NROWS; i += 256) vals[i] = src[i];
  __syncthreads();

  auto mkkey = [](float v, int i) -> u64 {
    unsigned u = __float_as_uint(v);
    u = ((int)u < 0) ? ~u : (u | 0x80000000u);
    return ((u64)u << 32) | (u64)(0xFFFFFFFFu - (unsigned)i);
  };

  u64 lk = 0;
#pragma unroll
  for (int m = 0; m < 32; ++m) {
    int i = t + 256 * m;
    lk = umax64(lk, mkkey(vals[i], i));
  }

  const int lane = t & 63, wv = t >> 6;
  for (int it = 0; it < KSEL; ++it) {
    u64 wk = lk;
#pragma unroll
    for (int s = 32; s > 0; s >>= 1) {
      u64 o = __shfl_xor(wk, s);
      wk = umax64(wk, o);
    }
    if (lane == 0) wmax[wv] = wk;
    __syncthreads();
    u64 g = umax64(umax64(wmax[0], wmax[1]), umax64(wmax[2], wmax[3]));
    const unsigned ui = (unsigned)(g >> 32);
    const float v = __uint_as_float((ui & 0x80000000u) ? (ui ^ 0x80000000u) : ~ui);
    const int idx = (int)(0xFFFFFFFFu - (unsigned)(g & 0xFFFFFFFFull));
    if (t == 0) { outv[it] = v; outi[it] = idx; }
    if (t == (idx & 255)) {
      vals[idx] = -INFINITY;
      u64 nl = 0;
#pragma unroll
      for (int m = 0; m < 32; ++m) {
        int i = t + 256 * m;
        nl = umax64(nl, mkkey(vals[i], i));
      }
      lk = nl;
    }
    __syncthreads();
  }
  if (t < KSEL) {
    topv[(size_t)row * KSEL + t] = outv[t];
    topi[(size_t)row * KSEL + t] = outi[t];
  }
  if (t == 0) {
    float s = 0.f;
#pragma unroll
    for (int q = 0; q < 10; ++q) s += outv[q];
    exps[row] = expf(s / 40.0f);
  }
}

// ---------------- K3: adjacency build + row softmax ----------------
__global__ __launch_bounds__(256) void k_adj(const int* __restrict__ indexes,
                                             const float* __restrict__ topv, const int* __restrict__ topi,
                                             const float* __restrict__ exps, float* __restrict__ adj) {
  __shared__ int nbr[64];
  __shared__ int neigh[64][10];
  __shared__ float tv[64][10];
  __shared__ float adjL[64][64];
  const int b = blockIdx.x;
  const int t = threadIdx.x;
  const int idx = indexes[b];
  if (t < 64) nbr[t] = topi[(size_t)idx * KSEL + t];
  __syncthreads();
  for (int p = t; p < 640; p += 256) {
    const int r = p / 10, q = p - r * 10;
    const int m = nbr[r];
    const int c = topi[(size_t)m * KSEL + q];
    neigh[r][q] = c;
    tv[r][q] = topv[(size_t)m * KSEL + q] * exps[c];
  }
  __syncthreads();
  for (int p = t; p < 4096; p += 256) {
    const int i = p >> 6, j = p & 63;
    float s = 0.f;
#pragma unroll
    for (int q = 0; q < 10; ++q) {
      const int c = neigh[i][q];
      float add = 0.f;
      for (int s2 = 0; s2 < 10; ++s2) {
        if (neigh[j][s2] == c) { add = (tv[j][s2] > 0.f) ? tv[i][q] : 0.f; break; }
      }
      s += add;
    }
    adjL[i][j] = s;
  }
  __syncthreads();
  const int wv = t >> 6, lane = t & 63;
  for (int i = wv * 16; i < wv * 16 + 16; ++i) {
    float v = adjL[i][lane];
    float mx = v;
#pragma unroll
    for (int s = 32; s > 0; s >>= 1) mx = fmaxf(mx, __shfl_xor(mx, s));
    float e = expf(v - mx);
    float sum = e;
#pragma unroll
    for (int s = 32; s > 0; s >>= 1) sum += __shfl_xor(sum, s);
    adj[((size_t)b * 64 + i) * 64 + lane] = e / sum;
  }
}

// ---------------- K4: xs splits ----------------
__global__ __launch_bounds__(256) void k_xs_split(const int* __restrict__ indexes, const int* __restrict__ topi,
                                                  const float* __restrict__ F,
                                                  ushort* __restrict__ XH, ushort* __restrict__ XL) {
  const int b = blockIdx.y, r = blockIdx.x;
  const int t = threadIdx.x;
  const int idx = indexes[b];
  const int m  = topi[(size_t)idx * KSEL + r];
  const int m0 = topi[(size_t)idx * KSEL + 0];
  const float4* pa = (const float4*)(F + (size_t)m * DFEAT);
  const float4* pb = (const float4*)(F + (size_t)m0 * DFEAT);
  const size_t rowoff = ((size_t)b * 64 + r) * DFEAT;
#pragma unroll
  for (int it = 0; it < 2; ++it) {
    const int i = t + it * 256;
    float4 a = pa[i], c = pb[i];
    float d[4] = {a.x - c.x, a.y - c.y, a.z - c.z, a.w - c.w};
    ushort h[4], l[4];
#pragma unroll
    for (int q = 0; q < 4; ++q) split2(d[q], h[q], l[q]);
    ushort4 vh = {h[0], h[1], h[2], h[3]};
    ushort4 vl = {l[0], l[1], l[2], l[3]};
    *(ushort4*)(XH + rowoff + i * 4) = vh;
    *(ushort4*)(XL + rowoff + i * 4) = vl;
  }
}

// ---------------- K5: weight pre-split, transposed + combined ----------------
__global__ __launch_bounds__(256) void k_wsplitT(const float* __restrict__ W,
                                                 ushort* __restrict__ WTH, ushort* __restrict__ WTL,
                                                 int K, int F) {
  __shared__ float tile[32][33];
  const int k0 = blockIdx.x * 32;
  const int n0 = blockIdx.y * 32;
  const int t = threadIdx.x;
  {
    const int r = t >> 3, cq = t & 7;
    const int srcRow = (n0 < F) ? (k0 + r) : (K + k0 + r);
    const int srcCol = (n0 < F) ? n0 : (n0 - F);
    float4 v = *(const float4*)(W + (size_t)srcRow * F + srcCol + cq * 4);
    tile[r][cq * 4 + 0] = v.x; tile[r][cq * 4 + 1] = v.y;
    tile[r][cq * 4 + 2] = v.z; tile[r][cq * 4 + 3] = v.w;
  }
  __syncthreads();
  {
    const int nl = t >> 3, kq = t & 7;
    ushort h[4], l[4];
#pragma unroll
    for (int i = 0; i < 4; ++i) split2(tile[kq * 4 + i][nl], h[i], l[i]);
    ushort4 vh = {h[0], h[1], h[2], h[3]};
    ushort4 vl = {l[0], l[1], l[2], l[3]};
    *(ushort4*)(WTH + (size_t)(n0 + nl) * K + k0 + kq * 4) = vh;
    *(ushort4*)(WTL + (size_t)(n0 + nl) * K + k0 + kq * 4) = vl;
  }
}

// ---------------- K6: layer epilogue: h = relu(P + adj@Q + bias); out splits ----------------
__global__ __launch_bounds__(256) void k_postlayer(const float* __restrict__ C, const float* __restrict__ adj,
                                                   const float* __restrict__ bias,
                                                   ushort* __restrict__ HH, ushort* __restrict__ HL, int F) {
  __shared__ float adjL[64 * 65];
  __shared__ float QL[64 * 66];
  const int f0 = blockIdx.x * 64;
  const int b = blockIdx.y;
  const int t = threadIdx.x;
  const int fc = t & 63, rg = t >> 6;
  const int twoF = 2 * F;
  for (int i = t; i < 4096; i += 256) {
    const int r = i >> 6, j = i & 63;
    adjL[r * 65 + j] = adj[(size_t)b * 4096 + i];
    QL[r * 66 + j] = C[(size_t)(b * 64 + r) * twoF + F + f0 + j];
  }
  __syncthreads();
  const float bv = bias[f0 + fc];
  for (int rr = 0; rr < 16; ++rr) {
    const int r = rg * 16 + rr;
    float s = 0.f;
#pragma unroll 8
    for (int j0 = 0; j0 < 64; ++j0) {
      const int j = (j0 + fc) & 63;
      s += adjL[r * 65 + j] * QL[j * 66 + fc];
    }
    const int row = b * 64 + r;
    float h = C[(size_t)row * twoF + f0 + fc] + s + bv;
    h = fmaxf(h, 0.f);
    ushort hh, hl;
    split2(h, hh, hl);
    HH[(size_t)row * F + f0 + fc] = hh;
    HL[(size_t)row * F + f0 + fc] = hl;
  }
}

// ---------------- K7: classifier epilogue: HC = prelu(C + bc1) ----------------
__global__ __launch_bounds__(256) void k_postcls(const float* __restrict__ C, const float* __restrict__ bias,
                                                 const float* __restrict__ pre, float* __restrict__ HC) {
  const size_t i0 = ((size_t)blockIdx.x * 256 + threadIdx.x) * 4;
  const int col = (int)(i0 & 255);
  float4 c = *(const float4*)(C + i0);
  float o[4] = {c.x, c.y, c.z, c.w};
#pragma unroll
  for (int i = 0; i < 4; ++i) {
    float h = o[i] + bias[col + i];
    o[i] = (h > 0.f) ? h : pre[col + i] * h;
  }
  *(float4*)(HC + i0) = make_float4(o[0], o[1], o[2], o[3]);
}

// ---------------- K8: pred = HC @ Wc2 + bc2 ----------------
__global__ __launch_bounds__(256) void k_final(const float* __restrict__ Hc, const float* __restrict__ Wc2,
                                               const float* __restrict__ bc2, float* __restrict__ outp) {
  __shared__ float w[512];
  __shared__ float red[512];
  const int t = threadIdx.x;
  for (int i = t; i < 512; i += 256) w[i] = Wc2[i];
  __syncthreads();
  const int m = blockIdx.x * 64 + (t >> 2);
  const int p = t & 3;
  const float* h = Hc + (size_t)m * 256;
  float s0 = 0.f, s1 = 0.f;
  for (int k = p * 64; k < p * 64 + 64; ++k) {
    float hv = h[k];
    s0 += hv * w[k * 2];
    s1 += hv * w[k * 2 + 1];
  }
  red[t * 2] = s0; red[t * 2 + 1] = s1;
  __syncthreads();
  if (p == 0) {
    for (int q = 1; q < 4; ++q) { s0 += red[(t + q) * 2]; s1 += red[(t + q) * 2 + 1]; }
    outp[m * 2 + 0] = s0 + bc2[0];
    outp[m * 2 + 1] = s1 + bc2[1];
  }
}

extern "C" void kernel_launch(void* const* d_in, const int* in_sizes, int n_in,
                              void* d_out, int out_size, void* d_ws, size_t ws_size,
                              hipStream_t stream) {
  const int*   indexes = (const int*)d_in[0];
  const float* F   = (const float*)d_in[1];
  const float* W1  = (const float*)d_in[4];
  const float* b1  = (const float*)d_in[5];
  const float* W2  = (const float*)d_in[6];
  const float* b2  = (const float*)d_in[7];
  const float* W3  = (const float*)d_in[8];
  const float* b3  = (const float*)d_in[9];
  const float* W4  = (const float*)d_in[10];
  const float* b4  = (const float*)d_in[11];
  const float* Wc1 = (const float*)d_in[12];
  const float* bc1 = (const float*)d_in[13];
  const float* pre = (const float*)d_in[14];
  const float* Wc2 = (const float*)d_in[15];
  const float* bc2 = (const float*)d_in[16];
  float* out = (float*)d_out;

  // ---- fixed workspace ----
  size_t off = 0;
  auto take = [&](size_t bytes) -> char* {
    char* q = (char*)d_ws + off;
    off += (bytes + 255) & ~(size_t)255;
    return q;
  };
  float* TOPV = (float*)take((size_t)NROWS * KSEL * 4);
  int*   TOPI = (int*)  take((size_t)NROWS * KSEL * 4);
  float* EXPS = (float*)take((size_t)NROWS * 4);
  float* ADJ  = (float*)take((size_t)64 * 64 * 64 * 4);
  char*  big  = (char*)d_ws + off;
  const size_t big_bytes = (ws_size > off) ? (ws_size - off) : 0;

  const size_t Mi = 1024 * 1024;
  const size_t Ki = 1024;

  const size_t splitBytes = (size_t)NROWS * DFEAT * 2;  // 32 Mi per split of F
  int fchunk = 0;
  for (int c = 2048; c >= 512; c >>= 1) {
    if (3 * splitBytes + (size_t)c * NROWS * 4 <= big_bytes) { fchunk = c; break; }
  }
  if (fchunk == 0) {
    hipMemsetAsync(d_out, 0, (size_t)out_size * 4, stream);
    return;
  }

  // ---- phase A: F splits + chunked sim panel + top-k ----
  {
    ushort* FH = (ushort*)big;
    ushort* FM = (ushort*)(big + splitBytes);
    ushort* FL = (ushort*)(big + 2 * splitBytes);
    float* SIMC = (float*)(big + 3 * splitBytes);
    k_split<<<NROWS * DFEAT / 1024, 256, 0, stream>>>(F, FH, FM, FL);
    for (int r0 = 0; r0 < NROWS; r0 += fchunk) {
      k_simgemm_mfma<<<dim3(64, fchunk / 128), 256, 0, stream>>>(FH, FM, FL, SIMC, r0);
      k_topk<<<fchunk, 256, 0, stream>>>(SIMC, TOPV, TOPI, EXPS, r0);
    }
  }
  k_adj<<<64, 256, 0, stream>>>(indexes, TOPV, TOPI, EXPS, ADJ);

  // ---- phase B layout (aliases phase-A region; lifetime-checked) ----
  // sizes: XH/XL 16Mi ea; WT1 8Mi/split; WT2 2Mi; WT3 .5Mi; WT4 .25Mi; WTc .125Mi
  //        CBUF 32Mi; HC 4Mi; H1 8Mi/split; H2 4Mi/split; H3 2Mi/split; H4 2Mi/split
  ushort* XH   = (ushort*)(big);                         //  0..16 Mi
  ushort* XL   = (ushort*)(big + 16 * Mi);               // 16..32 Mi
  ushort* WT1H = (ushort*)(big + 32 * Mi);               // 32..40 Mi
  ushort* WT1L = (ushort*)(big + 40 * Mi);               // 40..48 Mi
  ushort* WT2H = (ushort*)(big + 48 * Mi);               // 48..50 Mi
  ushort* WT2L = (ushort*)(big + 50 * Mi);               // 50..52 Mi
  ushort* WT3H = (ushort*)(big + 52 * Mi);               // 52..52.5 Mi
  ushort* WT3L = (ushort*)(big + 52 * Mi + 512 * Ki);    // 52.5..53 Mi
  ushort* WT4H = (ushort*)(big + 53 * Mi);               // 53..53.25 Mi
  ushort* WT4L = (ushort*)(big + 53 * Mi + 256 * Ki);    // 53.25..53.5 Mi
  ushort* WTcH = (ushort*)(big + 53 * Mi + 512 * Ki);    // 53.5..53.625 Mi
  ushort* WTcL = (ushort*)(big + 53 * Mi + 640 * Ki);    // 53.625..53.75 Mi
  float*  CBUF = (float*)(big + 54 * Mi);                // 54..86 Mi
  float*  HC   = (float*)(big + 86 * Mi);                // 86..90 Mi
  // H1 aliases WT1 (dead after L1 gemm): 8 Mi each, exact fit
  ushort* H1H  = (ushort*)(big + 32 * Mi);
  ushort* H1L  = (ushort*)(big + 40 * Mi);
  // H2/H3/H4 alias XS region (dead after L1 gemm): 4+4, 2+2, 2+2 Mi within 0..16 Mi
  ushort* H2H  = (ushort*)(big);                         //  0..4 Mi
  ushort* H2L  = (ushort*)(big + 4 * Mi);                //  4..8 Mi
  ushort* H3H  = (ushort*)(big + 8 * Mi);                //  8..10 Mi
  ushort* H3L  = (ushort*)(big + 10 * Mi);               // 10..12 Mi
  ushort* H4H  = (ushort*)(big + 12 * Mi);               // 12..14 Mi
  ushort* H4L  = (ushort*)(big + 14 * Mi);               // 14..16 Mi

  // weight pre-splits (phase-A big region dead)
  k_wsplitT<<<dim3(2048 / 32, 2048 / 32), 256, 0, stream>>>(W1, WT1H, WT1L, 2048, 1024);
  k_wsplitT<<<dim3(1024 / 32, 1024 / 32), 256, 0, stream>>>(W2, WT2H, WT2L, 1024, 512);
  k_wsplitT<<<dim3(512 / 32, 512 / 32), 256, 0, stream>>>(W3, WT3H, WT3L, 512, 256);
  k_wsplitT<<<dim3(256 / 32, 512 / 32), 256, 0, stream>>>(W4, WT4H, WT4L, 256, 256);
  k_wsplitT<<<dim3(256 / 32, 256 / 32), 256, 0, stream>>>(Wc1, WTcH, WTcL, 256, 256);

  k_xs_split<<<dim3(64, 64), 256, 0, stream>>>(indexes, TOPI, F, XH, XL);

  // L1: C = XS @ WT1^T (4096 x 2048); h1 = relu(P + adj@Q + b1) -> H1 (F=1024)
  k_gemm3<<<dim3(16, 32), 256, 0, stream>>>(XH, XL, WT1H, WT1L, CBUF, 2048, 2048);
  k_postlayer<<<dim3(16, 64), 256, 0, stream>>>(CBUF, ADJ, b1, H1H, H1L, 1024);
  // L2: K=1024, N=1024 -> H2 (F=512)
  k_gemm3<<<dim3(8, 32), 256, 0, stream>>>(H1H, H1L, WT2H, WT2L, CBUF, 1024, 1024);
  k_postlayer<<<dim3(8, 64), 256, 0, stream>>>(CBUF, ADJ, b2, H2H, H2L, 512);
  // L3: K=512, N=512 -> H3 (F=256)
  k_gemm3<<<dim3(4, 32), 256, 0, stream>>>(H2H, H2L, WT3H, WT3L, CBUF, 512, 512);
  k_postlayer<<<dim3(4, 64), 256, 0, stream>>>(CBUF, ADJ, b3, H3H, H3L, 256);
  // L4: K=256, N=512 -> H4 (F=256)
  k_gemm3<<<dim3(4, 32), 256, 0, stream>>>(H3H, H3L, WT4H, WT4L, CBUF, 256, 512);
  k_postlayer<<<dim3(4, 64), 256, 0, stream>>>(CBUF, ADJ, b4, H4H, H4L, 256);
  // classifier: K=256, N=256; HC = prelu(C + bc1)
  k_gemm3<<<dim3(2, 32), 256, 0, stream>>>(H4H, H4L, WTcH, WTcL, CBUF, 256, 256);
  k_postcls<<<4096 * 256 / 1024, 256, 0, stream>>>(CBUF, bc1, pre, HC);

  k_final<<<64, 256, 0, stream>>>(HC, Wc2, bc2, out);
}